// Round 6
// baseline (106.943 us; speedup 1.0000x reference)
//
#include <hip/hip_runtime.h>
#include <stdint.h>

// Problem constants: B=32, S=10, D=4096, K=8192
#define B_ 32
#define S_ 10
#define D_ 4096
#define K_ 8192
#define RPB 21                 // rows per batch in A: 10 pq + 10 pp + 1 qq
#define M_REAL (B_ * RPB)      // 672

#define BM 128
#define BN 128
#define BK 32
#define M_PAD_MF 768           // 6 tiles of 128
#define KSPLIT 2
#define KHALF (D_ / KSPLIT)    // 2048
#define NSTEP (KHALF / BK)     // 64

typedef _Float16 f16x8 __attribute__((ext_vector_type(8)));
typedef float f32x4 __attribute__((ext_vector_type(4)));
typedef unsigned short us4 __attribute__((ext_vector_type(4)));

__device__ __forceinline__ void async16(const void* g, void* l) {
  __builtin_amdgcn_global_load_lds(
      (const __attribute__((address_space(1))) unsigned int*)g,
      (__attribute__((address_space(3))) unsigned int*)l, 16, 0, 0);
}

// ---------------------------------------------------------------------------
// Prepass: build A rows (pq / pp / qq), quantize to a single f16 plane.
// ---------------------------------------------------------------------------
__global__ __launch_bounds__(256)
void build_a_f16(const float* __restrict__ p, const float* __restrict__ q,
                 unsigned short* __restrict__ Af) {
  size_t idx = (size_t)blockIdx.x * 256 + threadIdx.x;  // over M_PAD_MF * 1024 float4s
  int d4 = (int)(idx & 1023);
  int m = (int)(idx >> 10);
  float4 v = make_float4(0.f, 0.f, 0.f, 0.f);
  if (m < M_REAL) {
    int b = m / RPB;
    int r = m - b * RPB;
    const float4* q4 = (const float4*)(q + (size_t)(b * S_ + (S_ - 1)) * D_);
    if (r < S_) {
      const float4* p4 = (const float4*)(p + (size_t)(b * S_ + r) * D_);
      float4 pv = p4[d4]; float4 qv = q4[d4];
      v = make_float4(pv.x * qv.x, pv.y * qv.y, pv.z * qv.z, pv.w * qv.w);
    } else if (r < 2 * S_) {
      const float4* p4 = (const float4*)(p + (size_t)(b * S_ + (r - S_)) * D_);
      float4 pv = p4[d4];
      v = make_float4(pv.x * pv.x, pv.y * pv.y, pv.z * pv.z, pv.w * pv.w);
    } else {
      float4 qv = q4[d4];
      v = make_float4(qv.x * qv.x, qv.y * qv.y, qv.z * qv.z, qv.w * qv.w);
    }
  }
  us4 h;
  ((unsigned short*)&h)[0] = (unsigned short)__builtin_bit_cast(unsigned short, (_Float16)v.x);
  ((unsigned short*)&h)[1] = (unsigned short)__builtin_bit_cast(unsigned short, (_Float16)v.y);
  ((unsigned short*)&h)[2] = (unsigned short)__builtin_bit_cast(unsigned short, (_Float16)v.z);
  ((unsigned short*)&h)[3] = (unsigned short)__builtin_bit_cast(unsigned short, (_Float16)v.w);
  ((us4*)Af)[idx] = h;
}

// ---------------------------------------------------------------------------
// Fused MFMA GEMM: G[ks][m][k] = sum_{d in half ks} Af[m][d] * (W[k][d])^2
// Single-barrier-per-step full double-buffer pipeline:
//   LDS: Abuf0 [0,8K) Abuf1 [8K,16K) Wbuf0 [16K,24K) Wbuf1 [24K,32K)
//   iter i: {issue A-DMA(i+1)->Abuf[!cur]; load W-regs(i+1)} ;
//           ds_read+MFMA on buf[cur] ; cvt+ds_write W(i+1)->Wbuf[!cur] ;
//           __syncthreads()   (its vmcnt(0) drain lands a full step after issue)
// Safety: any wave in iter i has passed barrier(i-1), so all iter(i-1) reads
// of buf[!cur] are complete before staging overwrites it.  One barrier/step.
// 16B-chunk XOR swizzle  phys_chunk = chunk ^ ((row^(row>>2))&3)  on all tiles.
// ---------------------------------------------------------------------------
__global__ __launch_bounds__(256)
void gemm_mfma(const unsigned short* __restrict__ Af, const float* __restrict__ W,
               float* __restrict__ G) {
  __shared__ unsigned short lds[4 * 128 * 32];   // 32 KB
  const int tid = threadIdx.x;
  const int lane = tid & 63;
  const int wid = tid >> 6;
  const int m0 = blockIdx.y * BM;
  const int n0 = blockIdx.x * BN;
  const int ks = blockIdx.z;
  const int d_base = ks * KHALF;

  char* const ldsb = (char*)lds;          // A buffers at 0, 8192
  char* const ldsWb = ldsb + 16384;       // W buffers at 16384, 24576

  // ---- A staging: 2 async DMA issues per k-step, pre-swizzled global src ----
  const unsigned short* gpA[2];
  uint32_t ldsoffA[2];                    // within an A buffer (0..8K)
#pragma unroll
  for (int half = 0; half < 2; ++half) {
    int row = half * 64 + wid * 16 + (lane >> 2);
    int k16l = (lane & 3) ^ ((row ^ (row >> 2)) & 3);
    gpA[half] = Af + (size_t)(m0 + row) * D_ + d_base + k16l * 8;
    ldsoffA[half] = (uint32_t)(half * 4096 + wid * 1024);   // bytes
  }

  // ---- W staging: thread t covers row=t>>1, floats [h*16, h*16+16) ----
  const int wrow = tid >> 1;
  const int wh = tid & 1;
  const float* gW = W + (size_t)(n0 + wrow) * D_ + d_base + wh * 16;
  const int wsz = (wrow ^ (wrow >> 2)) & 3;
  const uint32_t wbyte0 = (uint32_t)(wrow * 64 + ((2 * wh) ^ wsz) * 16);
  const uint32_t wbyte1 = (uint32_t)(wrow * 64 + ((2 * wh + 1) ^ wsz) * 16);

  f32x4 acc[4][4];
#pragma unroll
  for (int i = 0; i < 4; ++i)
#pragma unroll
    for (int j = 0; j < 4; ++j) acc[i][j] = (f32x4){0.f, 0.f, 0.f, 0.f};

  const int wm = wid >> 1;        // wave row in 2x2 grid
  const int wn = wid & 1;
  const int frow = lane & 15;
  const int k16l = lane >> 4;
  int aoff[4], woff[4];           // byte offsets of fragments within a tile
#pragma unroll
  for (int f = 0; f < 4; ++f) {
    int ra = wm * 64 + f * 16 + frow;
    aoff[f] = ra * 64 + ((k16l ^ ((ra ^ (ra >> 2)) & 3)) * 16);
    int rw = wn * 64 + f * 16 + frow;
    woff[f] = rw * 64 + ((k16l ^ ((rw ^ (rw >> 2)) & 3)) * 16);
  }

  // ---- prologue: stage step 0 (A via DMA, W via reg+cvt), exposed once ----
  async16(gpA[0], ldsb + ldsoffA[0]);
  async16(gpA[1], ldsb + ldsoffA[1]);
  {
    float4 w0 = *(const float4*)(gW);
    float4 w1 = *(const float4*)(gW + 4);
    float4 w2 = *(const float4*)(gW + 8);
    float4 w3 = *(const float4*)(gW + 12);
    f16x8 o0, o1;
    o0[0] = (_Float16)(w0.x * w0.x); o0[1] = (_Float16)(w0.y * w0.y);
    o0[2] = (_Float16)(w0.z * w0.z); o0[3] = (_Float16)(w0.w * w0.w);
    o0[4] = (_Float16)(w1.x * w1.x); o0[5] = (_Float16)(w1.y * w1.y);
    o0[6] = (_Float16)(w1.z * w1.z); o0[7] = (_Float16)(w1.w * w1.w);
    o1[0] = (_Float16)(w2.x * w2.x); o1[1] = (_Float16)(w2.y * w2.y);
    o1[2] = (_Float16)(w2.z * w2.z); o1[3] = (_Float16)(w2.w * w2.w);
    o1[4] = (_Float16)(w3.x * w3.x); o1[5] = (_Float16)(w3.y * w3.y);
    o1[6] = (_Float16)(w3.z * w3.z); o1[7] = (_Float16)(w3.w * w3.w);
    *(f16x8*)(ldsWb + wbyte0) = o0;
    *(f16x8*)(ldsWb + wbyte1) = o1;
  }
  __syncthreads();   // step-0 tiles visible

  for (int i = 0; i < NSTEP; ++i) {
    // ---- top: prefetch step i+1 (A-DMA + W fp32 regs) into the idle bufs ----
    const int dn = ((i + 1 < NSTEP) ? (i + 1) : i) * BK;   // clamped (safe reload)
    const uint32_t nb = (uint32_t)(((i + 1) & 1) * 8192);
    async16(gpA[0] + dn, ldsb + nb + ldsoffA[0]);
    async16(gpA[1] + dn, ldsb + nb + ldsoffA[1]);
    float4 w0 = *(const float4*)(gW + dn);
    float4 w1 = *(const float4*)(gW + dn + 4);
    float4 w2 = *(const float4*)(gW + dn + 8);
    float4 w3 = *(const float4*)(gW + dn + 12);

    // ---- compute step i from buf[i&1] ----
    const uint32_t cb = (uint32_t)((i & 1) * 8192);
    f16x8 aF[4];
#pragma unroll
    for (int f = 0; f < 4; ++f)
      aF[f] = *(const f16x8*)(ldsb + cb + aoff[f]);
#pragma unroll
    for (int nf = 0; nf < 4; ++nf) {
      f16x8 wF = *(const f16x8*)(ldsWb + cb + woff[nf]);
#pragma unroll
      for (int mf = 0; mf < 4; ++mf)
        acc[mf][nf] = __builtin_amdgcn_mfma_f32_16x16x32_f16(aF[mf], wF, acc[mf][nf], 0, 0, 0);
    }

    // ---- bottom: cvt + ds_write W(i+1) into Wbuf[!cur] ----
    f16x8 o0, o1;
    o0[0] = (_Float16)(w0.x * w0.x); o0[1] = (_Float16)(w0.y * w0.y);
    o0[2] = (_Float16)(w0.z * w0.z); o0[3] = (_Float16)(w0.w * w0.w);
    o0[4] = (_Float16)(w1.x * w1.x); o0[5] = (_Float16)(w1.y * w1.y);
    o0[6] = (_Float16)(w1.z * w1.z); o0[7] = (_Float16)(w1.w * w1.w);
    o1[0] = (_Float16)(w2.x * w2.x); o1[1] = (_Float16)(w2.y * w2.y);
    o1[2] = (_Float16)(w2.z * w2.z); o1[3] = (_Float16)(w2.w * w2.w);
    o1[4] = (_Float16)(w3.x * w3.x); o1[5] = (_Float16)(w3.y * w3.y);
    o1[6] = (_Float16)(w3.z * w3.z); o1[7] = (_Float16)(w3.w * w3.w);
    *(f16x8*)(ldsWb + nb + wbyte0) = o0;
    *(f16x8*)(ldsWb + nb + wbyte1) = o1;

    __syncthreads();   // single barrier: step i+1 tiles ready, step i reads done
  }

  // ---- C write: row=(lane>>4)*4+r, col=lane&15 (verified gfx950 C/D layout) ----
  float* Gp = G + (size_t)ks * M_PAD_MF * K_;
  const int crow = m0 + wm * 64;
  const int ccol = n0 + wn * 64;
#pragma unroll
  for (int mf = 0; mf < 4; ++mf)
#pragma unroll
    for (int nf = 0; nf < 4; ++nf)
#pragma unroll
      for (int r = 0; r < 4; ++r) {
        int row = crow + mf * 16 + (lane >> 4) * 4 + r;
        int col = ccol + nf * 16 + (lane & 15);
        Gp[(size_t)row * K_ + col] = acc[mf][nf][r];
      }
}

// ---------------------------------------------------------------------------
// Epilogue: sum K-split planes, normalize, transpose-write.
// out[b][k][s] = -dot / (sqrt(pp)*sqrt(qq)*D)
// ---------------------------------------------------------------------------
__global__ __launch_bounds__(256)
void epilogue2(const float* __restrict__ G, float* __restrict__ out) {
  __shared__ float buf[256 * S_];
  const int tid = threadIdx.x;
  const int b = blockIdx.y;
  const int k0 = blockIdx.x * 256;
  const int k = k0 + tid;
  const float* G0 = G + (size_t)b * RPB * K_ + k;
  const float* G1 = G0 + (size_t)M_PAD_MF * K_;
  float nq = sqrtf(G0[20 * K_] + G1[20 * K_]);
#pragma unroll
  for (int s = 0; s < S_; ++s) {
    float dot = G0[s * K_] + G1[s * K_];
    float pp = G0[(S_ + s) * K_] + G1[(S_ + s) * K_];
    buf[tid * S_ + s] = -dot / (sqrtf(pp) * nq * (float)D_);
  }
  __syncthreads();
  float* ob = out + ((size_t)b * K_ + k0) * S_;
  for (int i = tid; i < 256 * S_; i += 256) ob[i] = buf[i];
}

// ===========================================================================
extern "C" void kernel_launch(void* const* d_in, const int* in_sizes, int n_in,
                              void* d_out, int out_size, void* d_ws, size_t ws_size,
                              hipStream_t stream) {
  const float* p = (const float*)d_in[0];
  const float* q = (const float*)d_in[1];
  const float* W = (const float*)d_in[2];
  float* out = (float*)d_out;

  // ws layout: Af [768][4096] f16 (6291456 B) | G [2][768][8192] f32 (50331648 B)
  uint8_t* w = (uint8_t*)d_ws;
  unsigned short* Af = (unsigned short*)w;
  float* G = (float*)(w + 6291456);

  build_a_f16<<<(M_PAD_MF * (D_ / 4)) / 256, 256, 0, stream>>>(p, q, Af);
  dim3 ggrid(K_ / BN, M_PAD_MF / BM, KSPLIT);   // (64, 6, 2) = 768 blocks
  gemm_mfma<<<ggrid, 256, 0, stream>>>(Af, W, G);
  epilogue2<<<dim3(K_ / 256, B_), 256, 0, stream>>>(G, out);
}